// Round 7
// baseline (225.978 us; speedup 1.0000x reference)
//
#include <hip/hip_runtime.h>

// ---------------------------------------------------------------------------
// GCN 3-layer forward on MI355X — fp16 MFMA, index-prefetched wave-gather.
//   hs = (h@W) * dis[row]      (MFMA GEMM, fp32/fp16 in, fp32 acc, fp16 out)
//   out[n] = relu( dis[n] * (sum_in(n) hs[s] + hs[n]) + b )
// deg holds EDGE counts (memset 0); dis = rsqrt(deg+1); scan(deg) -> CSR off.
// ---------------------------------------------------------------------------

typedef _Float16 half8_t __attribute__((ext_vector_type(8)));
typedef _Float16 half4_t __attribute__((ext_vector_type(4)));
typedef float floatx16 __attribute__((ext_vector_type(16)));

__device__ __forceinline__ int edge_at(const void* p, long long i, int is64) {
    if (is64) return (int)((const long long*)p)[i];
    return ((const int*)p)[i];
}

// per-block int64 detection: odd 32-bit words of first 64 entries all zero
__device__ __forceinline__ int detect_is64_block(const void* ei) {
    __shared__ int s_is64;
    if (threadIdx.x == 0) {
        const int* q = (const int*)ei;
        int z = 1;
        for (int k = 1; k < 128; k += 2) {
            if (q[k] != 0) { z = 0; break; }
        }
        s_is64 = z;
    }
    __syncthreads();
    return s_is64;
}

__global__ void count_deg_kernel(const void* __restrict__ ei, int* __restrict__ deg, int E) {
    int is64 = detect_is64_block(ei);
    int e = blockIdx.x * blockDim.x + threadIdx.x;
    if (e < E) {
        int d = edge_at(ei, (long long)E + e, is64);
        atomicAdd(&deg[d], 1);
    }
}

// ---- block 0: exclusive scan of deg + dis=rsqrt(deg+1) + cursor ------------
// ---- blocks 1..: W[K][N] fp32 -> Wt[N][K] fp16 (all three weights) ---------
#define SCAN_THREADS 1024
#define SCAN_CHUNK 20
__global__ __launch_bounds__(SCAN_THREADS) void scan_prep_kernel(
        const int* __restrict__ deg, int* __restrict__ off, int* __restrict__ curs,
        float* __restrict__ dis, int N, int E,
        const float* __restrict__ W1, const float* __restrict__ W2,
        const float* __restrict__ W3, _Float16* __restrict__ Wt1,
        _Float16* __restrict__ Wt2, _Float16* __restrict__ Wt3) {
    if (blockIdx.x != 0) {
        int id = (blockIdx.x - 1) * SCAN_THREADS + threadIdx.x;
        if (id < 65536) {                       // W1: 256x256 -> Wt1[256][256]
            int n = id >> 8, k = id & 255;
            Wt1[n * 256 + k] = (_Float16)W1[k * 256 + n];
        } else if (id < 98304) {                // W2: 256x128 -> Wt2[128][256]
            int i = id - 65536;
            int n = i >> 8, k = i & 255;
            Wt2[n * 256 + k] = (_Float16)W2[k * 128 + n];
        } else if (id < 106496) {               // W3: 128x64 -> Wt3[64][128]
            int i = id - 98304;
            int n = i >> 7, k = i & 127;
            Wt3[n * 128 + k] = (_Float16)W3[k * 64 + n];
        }
        return;
    }
    __shared__ int sums[SCAN_THREADS];
    int t = threadIdx.x;
    int base = t * SCAN_CHUNK;
    int local[SCAN_CHUNK];
    if (base + SCAN_CHUNK <= N) {
        const int4* p = (const int4*)(deg + base);
        #pragma unroll
        for (int i = 0; i < SCAN_CHUNK / 4; ++i) {
            int4 v = p[i];
            local[4 * i] = v.x; local[4 * i + 1] = v.y;
            local[4 * i + 2] = v.z; local[4 * i + 3] = v.w;
        }
    } else {
        for (int i = 0; i < SCAN_CHUNK; ++i) {
            int idx = base + i;
            local[i] = (idx < N) ? deg[idx] : 0;
        }
    }
    int pre[SCAN_CHUNK];
    int s = 0;
    #pragma unroll
    for (int i = 0; i < SCAN_CHUNK; ++i) { pre[i] = s; s += local[i]; }
    sums[t] = s;
    __syncthreads();
    for (int d = 1; d < SCAN_THREADS; d <<= 1) {
        int v = (t >= d) ? sums[t - d] : 0;
        __syncthreads();
        sums[t] += v;
        __syncthreads();
    }
    int prefix = (t > 0) ? sums[t - 1] : 0;
    for (int i = 0; i < SCAN_CHUNK; ++i) {
        int idx = base + i;
        if (idx < N) {
            int o = prefix + pre[i];
            off[idx] = o; curs[idx] = o;
            dis[idx] = rsqrtf((float)(local[i] + 1));
        }
    }
    if (t == 0) off[N] = E;
}

__global__ void fill_kernel(const void* __restrict__ ei, int* __restrict__ cur,
                            int* __restrict__ csr, int E) {
    int is64 = detect_is64_block(ei);
    int e = blockIdx.x * blockDim.x + threadIdx.x;
    if (e < E) {
        int s = edge_at(ei, e, is64);
        int d = edge_at(ei, (long long)E + e, is64);
        int slot = atomicAdd(&cur[d], 1);
        csr[slot] = s;
    }
}

// ---- MFMA GEMM: C[M,N] = (A[M,K] @ Wt^T) * dis[row], fp16 out --------------
// AT = float (layer 1, converts in staging) or _Float16.
template <typename AT>
__global__ __launch_bounds__(256) void gemm_mfma_kernel(
        const AT* __restrict__ A, const _Float16* __restrict__ Wt,
        const float* __restrict__ dis, _Float16* __restrict__ C,
        int M, int N, int K) {
    constexpr int BM = 128, BN = 64, BK = 32, PAD = 8;
    __shared__ _Float16 As[BM][BK + PAD];
    __shared__ _Float16 Bs[BN][BK + PAD];
    __shared__ float disS[BM];
    const int tid = threadIdx.x;
    const int wave = tid >> 6, lane = tid & 63;
    const int row0 = blockIdx.x * BM, col0 = blockIdx.y * BN;

    if (tid < BM) { int r = row0 + tid; disS[tid] = (r < M) ? dis[r] : 0.f; }

    const int ar0 = tid >> 2, ar1 = ar0 + 64;
    const int ac  = (tid & 3) * 8;
    const int br  = tid >> 2;
    const int bc  = (tid & 3) * 8;
    const long long arow0 = (long long)(row0 + ar0) * K;
    const long long arow1 = (long long)(row0 + ar1) * K;
    const long long brow  = (long long)(col0 + br) * K;
    const bool a0ok = (row0 + ar0) < M, a1ok = (row0 + ar1) < M;
    const float4 f4z = make_float4(0.f, 0.f, 0.f, 0.f);

    float4 pa0lo = f4z, pa0hi = f4z, pa1lo = f4z, pa1hi = f4z, pb;

    auto loadA = [&](int k0) {
        if constexpr (sizeof(AT) == 2) {
            if (a0ok) pa0lo = *(const float4*)((const _Float16*)A + arow0 + k0 + ac);
            if (a1ok) pa1lo = *(const float4*)((const _Float16*)A + arow1 + k0 + ac);
        } else {
            const float* p0 = (const float*)A + arow0 + k0 + ac;
            const float* p1 = (const float*)A + arow1 + k0 + ac;
            if (a0ok) { pa0lo = *(const float4*)p0; pa0hi = *(const float4*)(p0 + 4); }
            if (a1ok) { pa1lo = *(const float4*)p1; pa1hi = *(const float4*)(p1 + 4); }
        }
        pb = *(const float4*)(Wt + brow + k0 + bc);
    };
    auto storeA = [&]() {
        if constexpr (sizeof(AT) == 2) {
            *(float4*)&As[ar0][ac] = pa0lo;
            *(float4*)&As[ar1][ac] = pa1lo;
        } else {
            half8_t h0, h1;
            h0[0] = (_Float16)pa0lo.x; h0[1] = (_Float16)pa0lo.y;
            h0[2] = (_Float16)pa0lo.z; h0[3] = (_Float16)pa0lo.w;
            h0[4] = (_Float16)pa0hi.x; h0[5] = (_Float16)pa0hi.y;
            h0[6] = (_Float16)pa0hi.z; h0[7] = (_Float16)pa0hi.w;
            h1[0] = (_Float16)pa1lo.x; h1[1] = (_Float16)pa1lo.y;
            h1[2] = (_Float16)pa1lo.z; h1[3] = (_Float16)pa1lo.w;
            h1[4] = (_Float16)pa1hi.x; h1[5] = (_Float16)pa1hi.y;
            h1[6] = (_Float16)pa1hi.z; h1[7] = (_Float16)pa1hi.w;
            *(half8_t*)&As[ar0][ac] = h0;
            *(half8_t*)&As[ar1][ac] = h1;
        }
        *(float4*)&Bs[br][bc] = pb;
    };

    loadA(0);
    storeA();
    __syncthreads();

    floatx16 acc0, acc1;
    #pragma unroll
    for (int i = 0; i < 16; ++i) { acc0[i] = 0.f; acc1[i] = 0.f; }

    const _Float16* ap  = &As[wave * 32 + (lane & 31)][(lane >> 5) * 8];
    const _Float16* bp0 = &Bs[lane & 31][(lane >> 5) * 8];
    const _Float16* bp1 = &Bs[32 + (lane & 31)][(lane >> 5) * 8];

    const int niter = K / BK;
    for (int it = 0; it < niter; ++it) {
        const bool more = (it + 1) < niter;
        if (more) loadA((it + 1) * BK);
        half8_t a0  = *(const half8_t*)ap;
        half8_t a1  = *(const half8_t*)(ap + 16);
        half8_t b00 = *(const half8_t*)bp0;
        half8_t b01 = *(const half8_t*)(bp0 + 16);
        half8_t b10 = *(const half8_t*)bp1;
        half8_t b11 = *(const half8_t*)(bp1 + 16);
        acc0 = __builtin_amdgcn_mfma_f32_32x32x16_f16(a0, b00, acc0, 0, 0, 0);
        acc1 = __builtin_amdgcn_mfma_f32_32x32x16_f16(a0, b10, acc1, 0, 0, 0);
        acc0 = __builtin_amdgcn_mfma_f32_32x32x16_f16(a1, b01, acc0, 0, 0, 0);
        acc1 = __builtin_amdgcn_mfma_f32_32x32x16_f16(a1, b11, acc1, 0, 0, 0);
        if (more) {
            __syncthreads();
            storeA();
            __syncthreads();
        }
    }

    const int colb = lane & 31, q = lane >> 5;
    #pragma unroll
    for (int r = 0; r < 16; ++r) {
        int rl = wave * 32 + (r & 3) + 8 * (r >> 2) + 4 * q;
        int row = row0 + rl;
        if (row >= M) continue;
        float d = disS[rl];
        C[(long long)row * N + col0 + colb]      = (_Float16)(acc0[r] * d);
        C[(long long)row * N + col0 + 32 + colb] = (_Float16)(acc1[r] * d);
    }
}

// ---- aggregation: wave/node, 16B lanes, multi-edge loads, idx prefetch -----
__device__ __forceinline__ void vload8h(float* d, const _Float16* p) {
    half8_t v = *(const half8_t*)p;
    #pragma unroll
    for (int i = 0; i < 8; ++i) d[i] = (float)v[i];
}

template <int F, bool OUT_HALF, int U>
__global__ __launch_bounds__(256) void agg_kernel(
        const _Float16* __restrict__ hs, const float* __restrict__ dis,
        const float* __restrict__ bias, const int* __restrict__ off,
        const int* __restrict__ csr, void* __restrict__ outv,
        int N, int do_relu) {
    constexpr int LPE = F / 8;     // lanes per edge-row (16B each)
    constexpr int EPL = 64 / LPE;  // edge rows per wave-load
    constexpr int STEP = U * EPL;  // edges per main-loop iter
    const int wave = threadIdx.x >> 6;
    const int lane = threadIdx.x & 63;
    const int n = blockIdx.x * 4 + wave;
    if (n >= N) return;
    const int fl = lane % LPE;     // feature slice
    const int es = lane / LPE;     // edge slot
    const int fo = fl * 8;

    float acc[8];
    if (es == 0) {
        vload8h(acc, hs + (long long)n * F + fo);  // self-loop term
    } else {
        #pragma unroll
        for (int v = 0; v < 8; ++v) acc[v] = 0.f;
    }

    const int s0 = off[n], s1 = off[n + 1];
    int j = s0;
    if (j + STEP <= s1) {
        // prime: indices for first full group
        int idx[U];
        #pragma unroll
        for (int u = 0; u < U; ++u) idx[u] = csr[j + u * EPL + es];
        for (;;) {
            const int jn = j + STEP;
            const bool more = (jn + STEP <= s1);
            // issue gathers for current group
            float v[U][8];
            #pragma unroll
            for (int u = 0; u < U; ++u)
                vload8h(v[u], hs + (long long)idx[u] * F + fo);
            // prefetch next group's indices while gathers are in flight
            int nidx[U];
            if (more) {
                #pragma unroll
                for (int u = 0; u < U; ++u) nidx[u] = csr[jn + u * EPL + es];
            }
            #pragma unroll
            for (int u = 0; u < U; ++u)
                #pragma unroll
                for (int k = 0; k < 8; ++k) acc[k] += v[u][k];
            j = jn;
            if (!more) break;
            #pragma unroll
            for (int u = 0; u < U; ++u) idx[u] = nidx[u];
        }
    }
    if (j < s1) {  // masked tail (< STEP edges)
        #pragma unroll
        for (int u = 0; u < U; ++u) {
            int e = j + u * EPL + es;
            if (e < s1) {
                float v[8];
                vload8h(v, hs + (long long)csr[e] * F + fo);
                #pragma unroll
                for (int k = 0; k < 8; ++k) acc[k] += v[k];
            }
        }
    }

    // fold edge-slot partials down to lanes < LPE
    #pragma unroll
    for (int offd = 32; offd >= LPE; offd >>= 1) {
        #pragma unroll
        for (int k = 0; k < 8; ++k) acc[k] += __shfl_down(acc[k], offd);
    }

    if (lane < LPE) {
        float d = dis[n];
        float4 b0 = *(const float4*)(bias + fo);
        float4 b1 = *(const float4*)(bias + fo + 4);
        float bb[8] = {b0.x, b0.y, b0.z, b0.w, b1.x, b1.y, b1.z, b1.w};
        float o[8];
        #pragma unroll
        for (int k = 0; k < 8; ++k) {
            float val = d * acc[k] + bb[k];
            o[k] = do_relu ? fmaxf(val, 0.f) : val;
        }
        if constexpr (OUT_HALF) {
            half8_t h;
            #pragma unroll
            for (int k = 0; k < 8; ++k) h[k] = (_Float16)o[k];
            *(half8_t*)((_Float16*)outv + (long long)n * F + fo) = h;
        } else {
            float* op = (float*)outv + (long long)n * F + fo;
            *(float4*)op       = make_float4(o[0], o[1], o[2], o[3]);
            *(float4*)(op + 4) = make_float4(o[4], o[5], o[6], o[7]);
        }
    }
}

// ---------------------------------------------------------------------------
extern "C" void kernel_launch(void* const* d_in, const int* in_sizes, int n_in,
                              void* d_out, int out_size, void* d_ws, size_t ws_size,
                              hipStream_t stream) {
    const float* x  = (const float*)d_in[0];
    const float* W1 = (const float*)d_in[1];
    const float* b1 = (const float*)d_in[2];
    const float* W2 = (const float*)d_in[3];
    const float* b2 = (const float*)d_in[4];
    const float* W3 = (const float*)d_in[5];
    const float* b3 = (const float*)d_in[6];
    const void*  ei = d_in[7];

    const int N = in_sizes[0] / 256;      // 20000
    const int E = in_sizes[7] / 2;        // 320000

    size_t cur = 0;
    auto alloc = [&](size_t bytes) -> void* {
        void* p = (char*)d_ws + cur;
        cur += (bytes + 255) & ~(size_t)255;
        return p;
    };
    int*      deg  = (int*)alloc((size_t)N * 4);
    float*    dis  = (float*)alloc((size_t)N * 4);
    int*      off  = (int*)alloc((size_t)(N + 1) * 4);
    int*      curs = (int*)alloc((size_t)N * 4);
    int*      csr  = (int*)alloc((size_t)E * 4);
    _Float16* Wt1  = (_Float16*)alloc(256 * 256 * 2);
    _Float16* Wt2  = (_Float16*)alloc(128 * 256 * 2);
    _Float16* Wt3  = (_Float16*)alloc(64 * 128 * 2);
    _Float16* bufC = (_Float16*)alloc((size_t)N * 256 * 2);
    _Float16* bufH = (_Float16*)alloc((size_t)N * 256 * 2);
    (void)ws_size; (void)n_in; (void)out_size;

    const int T = 256;
    int gE = (E + T - 1) / T;
    int gAgg = (N + 3) / 4;
    int gScan = 1 + (106496 + SCAN_THREADS - 1) / SCAN_THREADS;  // 1 + 104

    hipMemsetAsync(deg, 0, (size_t)N * 4, stream);
    count_deg_kernel<<<gE, T, 0, stream>>>(ei, deg, E);
    scan_prep_kernel<<<gScan, SCAN_THREADS, 0, stream>>>(
        deg, off, curs, dis, N, E, W1, W2, W3, Wt1, Wt2, Wt3);
    fill_kernel<<<gE, T, 0, stream>>>(ei, curs, csr, E);

    int gM = (N + 127) / 128;  // 157

    gemm_mfma_kernel<float><<<dim3(gM, 4), 256, 0, stream>>>(x, Wt1, dis, bufC, N, 256, 256);
    agg_kernel<256, true, 6><<<gAgg, 256, 0, stream>>>(bufC, dis, b1, off, csr, bufH, N, 1);
    gemm_mfma_kernel<_Float16><<<dim3(gM, 2), 256, 0, stream>>>(bufH, Wt2, dis, bufC, N, 128, 256);
    agg_kernel<128, true, 4><<<gAgg, 256, 0, stream>>>(bufC, dis, b2, off, csr, bufH, N, 1);
    gemm_mfma_kernel<_Float16><<<dim3(gM, 1), 256, 0, stream>>>(bufH, Wt3, dis, bufC, N, 64, 128);
    agg_kernel<64, false, 4><<<gAgg, 256, 0, stream>>>(bufC, dis, b3, off, csr, d_out, N, 0);
}

// Round 8
// 217.912 us; speedup vs baseline: 1.0370x; 1.0370x over previous
//
#include <hip/hip_runtime.h>

// ---------------------------------------------------------------------------
// GCN 3-layer forward on MI355X — fp16 MFMA, fused-pipeline edition.
//   L1: hs_u = x@W1 (UNscaled);  agg1: out = relu(dis[n]*(Σ dis[s]*hs_u[s]
//        + dis[n]*hs_u[n]) + b)          (dis[src] folded into the gather)
//   L2/3: hs = (h@W)*dis[row];   agg:  out = relu(dis[n]*(Σ hs[s]+hs[n])+b)
// Launch graph (all serial on stream):
//   memset(deg) -> [count_deg | W-conv] -> scan -> [gemm1 | fill] ->
//   agg1 -> gemm2 -> agg2 -> gemm3 -> agg3
// ---------------------------------------------------------------------------

typedef _Float16 half8_t __attribute__((ext_vector_type(8)));
typedef float floatx16 __attribute__((ext_vector_type(16)));

// per-block int64 detection: odd 32-bit words of first 64 entries all zero
__device__ __forceinline__ int detect_is64_block(const void* ei) {
    __shared__ int s_is64;
    if (threadIdx.x == 0) {
        const int* q = (const int*)ei;
        int z = 1;
        for (int k = 1; k < 128; k += 2) {
            if (q[k] != 0) { z = 0; break; }
        }
        s_is64 = z;
    }
    __syncthreads();
    return s_is64;
}

// ---- count: 2 edges/thread -------------------------------------------------
__device__ void count_body(int blk, const void* ei, int* __restrict__ deg, int E) {
    int is64 = detect_is64_block(ei);
    int e0 = (blk * 256 + threadIdx.x) * 2;
    if (is64) {
        const long long* dst = (const long long*)ei + E;
        if (e0 + 1 < E) {
            int4 v = *(const int4*)(dst + e0);   // two little-endian int64
            atomicAdd(&deg[v.x], 1);
            atomicAdd(&deg[v.z], 1);
        } else if (e0 < E) {
            atomicAdd(&deg[(int)dst[e0]], 1);
        }
    } else {
        const int* dst = (const int*)ei + E;
        if (e0 + 1 < E) {
            int2 v = *(const int2*)(dst + e0);
            atomicAdd(&deg[v.x], 1);
            atomicAdd(&deg[v.y], 1);
        } else if (e0 < E) {
            atomicAdd(&deg[dst[e0]], 1);
        }
    }
}

// ---- W[K][N] fp32 -> Wt[N][K] fp16 ----------------------------------------
__device__ void wconv_body(int blk, const float* __restrict__ W1,
                           const float* __restrict__ W2, const float* __restrict__ W3,
                           _Float16* __restrict__ Wt1, _Float16* __restrict__ Wt2,
                           _Float16* __restrict__ Wt3) {
    int id = blk * 256 + threadIdx.x;
    if (id < 65536) {                       // W1: 256x256 -> Wt1[256][256]
        int n = id >> 8, k = id & 255;
        Wt1[n * 256 + k] = (_Float16)W1[k * 256 + n];
    } else if (id < 98304) {                // W2: 256x128 -> Wt2[128][256]
        int i = id - 65536;
        int n = i >> 8, k = i & 255;
        Wt2[n * 256 + k] = (_Float16)W2[k * 128 + n];
    } else if (id < 106496) {               // W3: 128x64 -> Wt3[64][128]
        int i = id - 98304;
        int n = i >> 7, k = i & 127;
        Wt3[n * 128 + k] = (_Float16)W3[k * 64 + n];
    }
}

// ---- fill CSR: 2 edges/thread ---------------------------------------------
__device__ void fill_body(int blk, const void* ei, int* __restrict__ cur,
                          int* __restrict__ csr, int E) {
    int is64 = detect_is64_block(ei);
    int e0 = (blk * 256 + threadIdx.x) * 2;
    int s0 = 0, s1 = 0, d0 = 0, d1 = 0, n = 0;
    if (is64) {
        const long long* src = (const long long*)ei;
        const long long* dst = src + E;
        if (e0 + 1 < E) {
            int4 vs = *(const int4*)(src + e0);
            int4 vd = *(const int4*)(dst + e0);
            s0 = vs.x; s1 = vs.z; d0 = vd.x; d1 = vd.z; n = 2;
        } else if (e0 < E) { s0 = (int)src[e0]; d0 = (int)dst[e0]; n = 1; }
    } else {
        const int* src = (const int*)ei;
        const int* dst = src + E;
        if (e0 + 1 < E) {
            int2 vs = *(const int2*)(src + e0);
            int2 vd = *(const int2*)(dst + e0);
            s0 = vs.x; s1 = vs.y; d0 = vd.x; d1 = vd.y; n = 2;
        } else if (e0 < E) { s0 = src[e0]; d0 = dst[e0]; n = 1; }
    }
    if (n >= 1) { int slot = atomicAdd(&cur[d0], 1); csr[slot] = s0; }
    if (n == 2) { int slot = atomicAdd(&cur[d1], 1); csr[slot] = s1; }
}

// ---- single-block scan: off/curs = exscan(deg), dis = rsqrt(deg+1) ---------
#define SCAN_THREADS 1024
#define SCAN_CHUNK 20
__global__ __launch_bounds__(SCAN_THREADS) void scan_kernel(
        const int* __restrict__ deg, int* __restrict__ off, int* __restrict__ curs,
        float* __restrict__ dis, int N, int E) {
    __shared__ int sums[SCAN_THREADS];
    int t = threadIdx.x;
    int base = t * SCAN_CHUNK;
    int local[SCAN_CHUNK];
    if (base + SCAN_CHUNK <= N) {
        const int4* p = (const int4*)(deg + base);
        #pragma unroll
        for (int i = 0; i < SCAN_CHUNK / 4; ++i) {
            int4 v = p[i];
            local[4 * i] = v.x; local[4 * i + 1] = v.y;
            local[4 * i + 2] = v.z; local[4 * i + 3] = v.w;
        }
    } else {
        for (int i = 0; i < SCAN_CHUNK; ++i) {
            int idx = base + i;
            local[i] = (idx < N) ? deg[idx] : 0;
        }
    }
    int pre[SCAN_CHUNK];
    int s = 0;
    #pragma unroll
    for (int i = 0; i < SCAN_CHUNK; ++i) { pre[i] = s; s += local[i]; }
    sums[t] = s;
    __syncthreads();
    for (int d = 1; d < SCAN_THREADS; d <<= 1) {
        int v = (t >= d) ? sums[t - d] : 0;
        __syncthreads();
        sums[t] += v;
        __syncthreads();
    }
    int prefix = (t > 0) ? sums[t - 1] : 0;
    for (int i = 0; i < SCAN_CHUNK; ++i) {
        int idx = base + i;
        if (idx < N) {
            int o = prefix + pre[i];
            off[idx] = o; curs[idx] = o;
            dis[idx] = rsqrtf((float)(local[i] + 1));
        }
    }
    if (t == 0) off[N] = E;
}

// ---- MFMA GEMM body: C = (A @ Wt^T) [* dis[row] if SCALE], fp16 out --------
template <typename AT, bool SCALE>
__device__ void gemm_body(int bx, int by, const AT* __restrict__ A,
                          const _Float16* __restrict__ Wt, const float* __restrict__ dis,
                          _Float16* __restrict__ C, int M, int N, int K) {
    constexpr int BM = 128, BN = 64, BK = 32, PAD = 8;
    __shared__ _Float16 As[BM][BK + PAD];
    __shared__ _Float16 Bs[BN][BK + PAD];
    __shared__ float disS[BM];
    const int tid = threadIdx.x;
    const int wave = tid >> 6, lane = tid & 63;
    const int row0 = bx * BM, col0 = by * BN;

    if constexpr (SCALE) {
        if (tid < BM) { int r = row0 + tid; disS[tid] = (r < M) ? dis[r] : 0.f; }
    }

    const int ar0 = tid >> 2, ar1 = ar0 + 64;
    const int ac  = (tid & 3) * 8;
    const int br  = tid >> 2;
    const int bc  = (tid & 3) * 8;
    const long long arow0 = (long long)(row0 + ar0) * K;
    const long long arow1 = (long long)(row0 + ar1) * K;
    const long long brow  = (long long)(col0 + br) * K;
    const bool a0ok = (row0 + ar0) < M, a1ok = (row0 + ar1) < M;
    const float4 f4z = make_float4(0.f, 0.f, 0.f, 0.f);

    float4 pa0lo = f4z, pa0hi = f4z, pa1lo = f4z, pa1hi = f4z, pb;

    auto loadA = [&](int k0) {
        if constexpr (sizeof(AT) == 2) {
            if (a0ok) pa0lo = *(const float4*)((const _Float16*)A + arow0 + k0 + ac);
            if (a1ok) pa1lo = *(const float4*)((const _Float16*)A + arow1 + k0 + ac);
        } else {
            const float* p0 = (const float*)A + arow0 + k0 + ac;
            const float* p1 = (const float*)A + arow1 + k0 + ac;
            if (a0ok) { pa0lo = *(const float4*)p0; pa0hi = *(const float4*)(p0 + 4); }
            if (a1ok) { pa1lo = *(const float4*)p1; pa1hi = *(const float4*)(p1 + 4); }
        }
        pb = *(const float4*)(Wt + brow + k0 + bc);
    };
    auto storeA = [&]() {
        if constexpr (sizeof(AT) == 2) {
            *(float4*)&As[ar0][ac] = pa0lo;
            *(float4*)&As[ar1][ac] = pa1lo;
        } else {
            half8_t h0, h1;
            h0[0] = (_Float16)pa0lo.x; h0[1] = (_Float16)pa0lo.y;
            h0[2] = (_Float16)pa0lo.z; h0[3] = (_Float16)pa0lo.w;
            h0[4] = (_Float16)pa0hi.x; h0[5] = (_Float16)pa0hi.y;
            h0[6] = (_Float16)pa0hi.z; h0[7] = (_Float16)pa0hi.w;
            h1[0] = (_Float16)pa1lo.x; h1[1] = (_Float16)pa1lo.y;
            h1[2] = (_Float16)pa1lo.z; h1[3] = (_Float16)pa1lo.w;
            h1[4] = (_Float16)pa1hi.x; h1[5] = (_Float16)pa1hi.y;
            h1[6] = (_Float16)pa1hi.z; h1[7] = (_Float16)pa1hi.w;
            *(half8_t*)&As[ar0][ac] = h0;
            *(half8_t*)&As[ar1][ac] = h1;
        }
        *(float4*)&Bs[br][bc] = pb;
    };

    loadA(0);
    storeA();
    __syncthreads();

    floatx16 acc0, acc1;
    #pragma unroll
    for (int i = 0; i < 16; ++i) { acc0[i] = 0.f; acc1[i] = 0.f; }

    const _Float16* ap  = &As[wave * 32 + (lane & 31)][(lane >> 5) * 8];
    const _Float16* bp0 = &Bs[lane & 31][(lane >> 5) * 8];
    const _Float16* bp1 = &Bs[32 + (lane & 31)][(lane >> 5) * 8];

    const int niter = K / BK;
    for (int it = 0; it < niter; ++it) {
        const bool more = (it + 1) < niter;
        if (more) loadA((it + 1) * BK);
        half8_t a0  = *(const half8_t*)ap;
        half8_t a1  = *(const half8_t*)(ap + 16);
        half8_t b00 = *(const half8_t*)bp0;
        half8_t b01 = *(const half8_t*)(bp0 + 16);
        half8_t b10 = *(const half8_t*)bp1;
        half8_t b11 = *(const half8_t*)(bp1 + 16);
        acc0 = __builtin_amdgcn_mfma_f32_32x32x16_f16(a0, b00, acc0, 0, 0, 0);
        acc1 = __builtin_amdgcn_mfma_f32_32x32x16_f16(a0, b10, acc1, 0, 0, 0);
        acc0 = __builtin_amdgcn_mfma_f32_32x32x16_f16(a1, b01, acc0, 0, 0, 0);
        acc1 = __builtin_amdgcn_mfma_f32_32x32x16_f16(a1, b11, acc1, 0, 0, 0);
        if (more) {
            __syncthreads();
            storeA();
            __syncthreads();
        }
    }

    const int colb = lane & 31, q = lane >> 5;
    #pragma unroll
    for (int r = 0; r < 16; ++r) {
        int rl = wave * 32 + (r & 3) + 8 * (r >> 2) + 4 * q;
        int row = row0 + rl;
        if (row >= M) continue;
        float d = SCALE ? disS[rl] : 1.0f;
        C[(long long)row * N + col0 + colb]      = (_Float16)(acc0[r] * d);
        C[(long long)row * N + col0 + 32 + colb] = (_Float16)(acc1[r] * d);
    }
}

// ---- fused launches --------------------------------------------------------
__global__ __launch_bounds__(256) void fused_count_wconv_kernel(
        const void* ei, int* deg, int E, int nCount,
        const float* W1, const float* W2, const float* W3,
        _Float16* Wt1, _Float16* Wt2, _Float16* Wt3) {
    if ((int)blockIdx.x < nCount) count_body(blockIdx.x, ei, deg, E);
    else wconv_body(blockIdx.x - nCount, W1, W2, W3, Wt1, Wt2, Wt3);
}

__global__ __launch_bounds__(256) void fused_gemm1_fill_kernel(
        const float* x, const _Float16* Wt1, _Float16* C, int M, int gM, int nGemm,
        const void* ei, int* cur, int* csr, int E) {
    if ((int)blockIdx.x < nGemm) {
        gemm_body<float, false>(blockIdx.x % gM, blockIdx.x / gM, x, Wt1, nullptr,
                                C, M, 256, 256);
    } else {
        fill_body(blockIdx.x - nGemm, ei, cur, csr, E);
    }
}

__global__ __launch_bounds__(256) void gemm_kernel(
        const _Float16* A, const _Float16* Wt, const float* dis, _Float16* C,
        int M, int N, int K) {
    gemm_body<_Float16, true>(blockIdx.x, blockIdx.y, A, Wt, dis, C, M, N, K);
}

// ---- aggregation: wave/node, 16B lanes, multi-edge wave-loads --------------
__device__ __forceinline__ void vload8h(float* d, const _Float16* p) {
    half8_t v = *(const half8_t*)p;
    #pragma unroll
    for (int i = 0; i < 8; ++i) d[i] = (float)v[i];
}

template <int F, bool OUT_HALF, int U, bool SCALE_SRC>
__global__ __launch_bounds__(256) void agg_kernel(
        const _Float16* __restrict__ hs, const float* __restrict__ dis,
        const float* __restrict__ bias, const int* __restrict__ off,
        const int* __restrict__ csr, void* __restrict__ outv,
        int N, int do_relu) {
    constexpr int LPE = F / 8;     // lanes per edge-row (16B each)
    constexpr int EPL = 64 / LPE;  // edge rows per wave-load
    constexpr int STEP = U * EPL;  // edges per main-loop iter
    const int wave = threadIdx.x >> 6;
    const int lane = threadIdx.x & 63;
    const int n = blockIdx.x * 4 + wave;
    if (n >= N) return;
    const int fl = lane % LPE;     // feature slice
    const int es = lane / LPE;     // edge slot
    const int fo = fl * 8;
    const float dn = dis[n];

    float acc[8];
    if (es == 0) {
        vload8h(acc, hs + (long long)n * F + fo);  // self-loop term
        if constexpr (SCALE_SRC) {
            #pragma unroll
            for (int k = 0; k < 8; ++k) acc[k] *= dn;
        }
    } else {
        #pragma unroll
        for (int v = 0; v < 8; ++v) acc[v] = 0.f;
    }

    const int s0 = off[n], s1 = off[n + 1];
    int j = s0;
    for (; j + STEP <= s1; j += STEP) {
        int idx[U];
        #pragma unroll
        for (int u = 0; u < U; ++u) idx[u] = csr[j + u * EPL + es];
        float ds[U];
        if constexpr (SCALE_SRC) {
            #pragma unroll
            for (int u = 0; u < U; ++u) ds[u] = dis[idx[u]];
        }
        float v[U][8];
        #pragma unroll
        for (int u = 0; u < U; ++u)
            vload8h(v[u], hs + (long long)idx[u] * F + fo);
        #pragma unroll
        for (int u = 0; u < U; ++u) {
            #pragma unroll
            for (int k = 0; k < 8; ++k)
                acc[k] += SCALE_SRC ? v[u][k] * ds[u] : v[u][k];
        }
    }
    if (j < s1) {  // masked tail
        #pragma unroll
        for (int u = 0; u < U; ++u) {
            int e = j + u * EPL + es;
            if (e < s1) {
                int ii = csr[e];
                float sc = SCALE_SRC ? dis[ii] : 1.0f;
                float v[8];
                vload8h(v, hs + (long long)ii * F + fo);
                #pragma unroll
                for (int k = 0; k < 8; ++k) acc[k] += v[k] * sc;
            }
        }
    }

    // fold edge-slot partials down to lanes < LPE
    #pragma unroll
    for (int offd = 32; offd >= LPE; offd >>= 1) {
        #pragma unroll
        for (int k = 0; k < 8; ++k) acc[k] += __shfl_down(acc[k], offd);
    }

    if (lane < LPE) {
        float4 b0 = *(const float4*)(bias + fo);
        float4 b1 = *(const float4*)(bias + fo + 4);
        float bb[8] = {b0.x, b0.y, b0.z, b0.w, b1.x, b1.y, b1.z, b1.w};
        float o[8];
        #pragma unroll
        for (int k = 0; k < 8; ++k) {
            float val = dn * acc[k] + bb[k];
            o[k] = do_relu ? fmaxf(val, 0.f) : val;
        }
        if constexpr (OUT_HALF) {
            half8_t h;
            #pragma unroll
            for (int k = 0; k < 8; ++k) h[k] = (_Float16)o[k];
            *(half8_t*)((_Float16*)outv + (long long)n * F + fo) = h;
        } else {
            float* op = (float*)outv + (long long)n * F + fo;
            *(float4*)op       = make_float4(o[0], o[1], o[2], o[3]);
            *(float4*)(op + 4) = make_float4(o[4], o[5], o[6], o[7]);
        }
    }
}

// ---------------------------------------------------------------------------
extern "C" void kernel_launch(void* const* d_in, const int* in_sizes, int n_in,
                              void* d_out, int out_size, void* d_ws, size_t ws_size,
                              hipStream_t stream) {
    const float* x  = (const float*)d_in[0];
    const float* W1 = (const float*)d_in[1];
    const float* b1 = (const float*)d_in[2];
    const float* W2 = (const float*)d_in[3];
    const float* b2 = (const float*)d_in[4];
    const float* W3 = (const float*)d_in[5];
    const float* b3 = (const float*)d_in[6];
    const void*  ei = d_in[7];

    const int N = in_sizes[0] / 256;      // 20000
    const int E = in_sizes[7] / 2;        // 320000

    size_t cur = 0;
    auto alloc = [&](size_t bytes) -> void* {
        void* p = (char*)d_ws + cur;
        cur += (bytes + 255) & ~(size_t)255;
        return p;
    };
    int*      deg  = (int*)alloc((size_t)N * 4);
    float*    dis  = (float*)alloc((size_t)N * 4);
    int*      off  = (int*)alloc((size_t)(N + 1) * 4);
    int*      curs = (int*)alloc((size_t)N * 4);
    int*      csr  = (int*)alloc((size_t)E * 4);
    _Float16* Wt1  = (_Float16*)alloc(256 * 256 * 2);
    _Float16* Wt2  = (_Float16*)alloc(128 * 256 * 2);
    _Float16* Wt3  = (_Float16*)alloc(64 * 128 * 2);
    _Float16* bufC = (_Float16*)alloc((size_t)N * 256 * 2);
    _Float16* bufH = (_Float16*)alloc((size_t)N * 256 * 2);
    (void)ws_size; (void)n_in; (void)out_size;

    const int gM   = (N + 127) / 128;            // 157
    const int nCnt = (E / 2 + 255) / 256;        // 625 (2 edges/thread)
    const int nWcv = (106496 + 255) / 256;       // 416
    const int nGm1 = gM * 4;                     // 628
    const int gAgg = (N + 3) / 4;

    hipMemsetAsync(deg, 0, (size_t)N * 4, stream);
    fused_count_wconv_kernel<<<nCnt + nWcv, 256, 0, stream>>>(
        ei, deg, E, nCnt, W1, W2, W3, Wt1, Wt2, Wt3);
    scan_kernel<<<1, SCAN_THREADS, 0, stream>>>(deg, off, curs, dis, N, E);
    fused_gemm1_fill_kernel<<<nGm1 + nCnt, 256, 0, stream>>>(
        x, Wt1, bufC, N, gM, nGm1, ei, curs, csr, E);

    agg_kernel<256, true, 4, true><<<gAgg, 256, 0, stream>>>(
        bufC, dis, b1, off, csr, bufH, N, 1);
    gemm_kernel<<<dim3(gM, 2), 256, 0, stream>>>(bufH, Wt2, dis, bufC, N, 128, 256);
    agg_kernel<128, true, 4, false><<<gAgg, 256, 0, stream>>>(
        bufC, dis, b2, off, csr, bufH, N, 1);
    gemm_kernel<<<dim3(gM, 1), 256, 0, stream>>>(bufH, Wt3, dis, bufC, N, 64, 128);
    agg_kernel<64, false, 2, false><<<gAgg, 256, 0, stream>>>(
        bufC, dis, b3, off, csr, d_out, N, 0);
}